// Round 10
// baseline (85.682 us; speedup 1.0000x reference)
//
#include <hip/hip_runtime.h>
#include <math.h>

#define HH 256
#define WW 256
#define BB 8
#define NTOT (BB*HH*WW)
#define LARGE_F 1000000.0f
#define SCOPE __HIP_MEMORY_SCOPE_AGENT

typedef unsigned int u32;
typedef unsigned long long u64;

// ONE dispatch, 128 blocks x 1024 threads (16 waves). 1 row/wave, 4 px/lane.
// 16 blocks/image. Cross-block sync is poison-keyed (published values are
// nonneg floats; 0xAA poison has sign bits set => sign-clear == ready).

__device__ __forceinline__ float wave_max(float v) {
    #pragma unroll
    for (int off = 32; off > 0; off >>= 1)
        v = fmaxf(v, __shfl_xor(v, off, 64));
    return v;
}

// ballot-build row's 256-bit mask into LDS (wave-uniform call; 64 lanes active)
__device__ __forceinline__ void build_row(const int* __restrict__ tgt, int tb,
                                          int row, int lane, u64 (*sm)[4]) {
    const int base = tb + (row << 8) + lane;
    u64 w0 = __ballot(tgt[base]       == 0);
    u64 w1 = __ballot(tgt[base + 64]  == 0);
    u64 w2 = __ballot(tgt[base + 128] == 0);
    u64 w3 = __ballot(tgt[base + 192] == 0);
    if (lane == 0) { sm[row][0] = w0; sm[row][1] = w1; sm[row][2] = w2; sm[row][3] = w3; }
}

// nearest set-bit distances within one 256-bit row mask (bit set = feature)
__device__ __forceinline__ void row_check(const u64* __restrict__ row,
                                          int k0, int r0, int c0, float dh2f,
                                          float* bestA, float* bestB) {
    u64 m0 = row[0], m1 = row[1], m2 = row[2], m3 = row[3];
    u64 n0 = ~m0, n1 = ~m1, n2 = ~m2, n3 = ~m3;

    int HbA = -1;
    if (k0 > 0 && m0) HbA = 63  - __builtin_clzll(m0);
    if (k0 > 1 && m1) HbA = 127 - __builtin_clzll(m1);
    if (k0 > 2 && m2) HbA = 191 - __builtin_clzll(m2);
    int RaA = 1 << 20;
    if (k0 < 3 && m3) RaA = 192 + __builtin_ctzll(m3);
    if (k0 < 2 && m2) RaA = 128 + __builtin_ctzll(m2);
    if (k0 < 1 && m1) RaA = 64  + __builtin_ctzll(m1);

    int HbB = -1;
    if (k0 > 0 && n0) HbB = 63  - __builtin_clzll(n0);
    if (k0 > 1 && n1) HbB = 127 - __builtin_clzll(n1);
    if (k0 > 2 && n2) HbB = 191 - __builtin_clzll(n2);
    int RaB = 1 << 20;
    if (k0 < 3 && n3) RaB = 192 + __builtin_ctzll(n3);
    if (k0 < 2 && n2) RaB = 128 + __builtin_ctzll(n2);
    if (k0 < 1 && n1) RaB = 64  + __builtin_ctzll(n1);

    u64 mk = (k0 == 0) ? m0 : (k0 == 1) ? m1 : (k0 == 2) ? m2 : m3;
    u64 nk = ~mk;
    const int base = 64 * k0;

    #pragma unroll
    for (int s = 0; s < 4; ++s) {
        int r = r0 + s, w = c0 + s;
        u64 le = (2ull << r) - 1ull;
        u64 ge = (~0ull) << r;
        {
            u64 lo = mk & le, hi = mk & ge;
            int L = lo ? (base + 63 - __builtin_clzll(lo)) : HbA;
            int R = hi ? (base + __builtin_ctzll(hi)) : RaA;
            int dl = (L >= 0) ? (w - L) : (1 << 20);
            int dr = R - w;
            float f = (float)min(dl, dr);
            bestA[s] = fminf(bestA[s], __builtin_fmaf(f, f, dh2f));
        }
        {
            u64 lo = nk & le, hi = nk & ge;
            int L = lo ? (base + 63 - __builtin_clzll(lo)) : HbB;
            int R = hi ? (base + __builtin_ctzll(hi)) : RaB;
            int dl = (L >= 0) ? (w - L) : (1 << 20);
            int dr = R - w;
            float f = (float)min(dl, dr);
            bestB[s] = fminf(bestB[s], __builtin_fmaf(f, f, dh2f));
        }
    }
}

__global__ void __launch_bounds__(1024) k_fused(
    const float* __restrict__ p0, const float* __restrict__ p1,
    const float* __restrict__ p2, const float* __restrict__ p3,
    const int* __restrict__ tgt,
    u64* __restrict__ slabAB, float* __restrict__ partial,
    float* __restrict__ out)
{
    const int blk  = blockIdx.x;
    const int b    = blk >> 4;        // image (16 blocks per image)
    const int slab = blk & 15;        // 16-row slab
    const int wv   = threadIdx.x >> 6;   // 0..15
    const int lane = threadIdx.x & 63;
    const int h    = slab * 16 + wv;  // this wave's row
    const int c0   = lane * 4;
    const int k0   = c0 >> 6;
    const int r0   = c0 & 63;
    const int tb   = b << 16;
    const int rowbase = tb + (h << 8);

    __shared__ u64 sm[HH][4];
    __shared__ float wredA[16], wredB[16], smdv[2];
    __shared__ float red[16][12];
    __shared__ float fing[96];

    // ---- cooperative initial window FIRST (critical path into EDT):
    //      rows [slab*16-8, slab*16+23], 2 rows per wave ----
    const int lo0 = slab * 16 - 8;
    #pragma unroll
    for (int j = 0; j < 2; ++j) {
        int row = lo0 + wv * 2 + j;
        if (row >= 0 && row < HH) build_row(tgt, tb, row, lane, sm);
    }

    // ---- pred loads issued now; consumed only after EDT ----
    const int idx = rowbase + c0;
    float4 x40 = *(const float4*)(p0 + idx);
    float4 x41 = *(const float4*)(p1 + idx);
    float4 x42 = *(const float4*)(p2 + idx);
    float4 x43 = *(const float4*)(p3 + idx);

    __syncthreads();
    int winLo = max(lo0, 0);
    int winHi = min(lo0 + 31, HH - 1);

    // ---- EDT ring search (wave-uniform loop, lazy row extension) ----
    float bestA[4] = {1e30f, 1e30f, 1e30f, 1e30f};
    float bestB[4] = {1e30f, 1e30f, 1e30f, 1e30f};

    row_check(&sm[h][0], k0, r0, c0, 0.0f, bestA, bestB);
    float bmax = 0.0f;
    #pragma unroll
    for (int s = 0; s < 4; ++s) bmax = fmaxf(bmax, fmaxf(bestA[s], bestB[s]));
    float wbmax = wave_max(bmax);

    for (int dh = 1; dh < HH; ++dh) {
        float dh2f = (float)(dh * dh);
        if (dh2f >= wbmax) break;                 // uniform on all lanes
        int hd = h - dh, hu = h + dh;
        if (hd >= 0) {
            if (hd < winLo) { build_row(tgt, tb, hd, lane, sm); winLo = hd; }
            row_check(&sm[hd][0], k0, r0, c0, dh2f, bestA, bestB);
        }
        if (hu < HH) {
            if (hu > winHi) { build_row(tgt, tb, hu, lane, sm); winHi = hu; }
            row_check(&sm[hu][0], k0, r0, c0, dh2f, bestA, bestB);
        }
        bmax = 0.0f;
        #pragma unroll
        for (int s = 0; s < 4; ++s) bmax = fmaxf(bmax, fmaxf(bestA[s], bestB[s]));
        wbmax = wave_max(bmax);
    }

    // best >= 1e29 only if that mask is empty image-wide => dist = exactly 1e6.
    const bool emptyB = (bestB[0] >= 1e29f);      // no t==1 pixels
    const u64 mkown = sm[h][k0];
    float absd[4], tfv[4];
    float wmA = -1.0f, wmB = -1.0f;
    #pragma unroll
    for (int s = 0; s < 4; ++s) {
        float dA = (bestA[s] >= 1e29f) ? LARGE_F : sqrtf(bestA[s]);
        float dB = (bestB[s] >= 1e29f) ? LARGE_F : sqrtf(bestB[s]);
        wmA = fmaxf(wmA, dA);
        wmB = fmaxf(wmB, dB);
        int bit = (int)((mkown >> (r0 + s)) & 1ull);   // set => t==0
        tfv[s]  = bit ? 0.0f : 1.0f;
        absd[s] = bit ? dB : dA;
    }
    #pragma unroll
    for (int off = 32; off > 0; off >>= 1) {
        wmA = fmaxf(wmA, __shfl_down(wmA, off, 64));
        wmB = fmaxf(wmB, __shfl_down(wmB, off, 64));
    }
    if (lane == 0) { wredA[wv] = wmA; wredB[wv] = wmB; }
    __syncthreads();
    if (threadIdx.x == 0) {
        float bA = wredA[0], bB = wredB[0];
        #pragma unroll
        for (int j = 1; j < 16; ++j) {
            bA = fmaxf(bA, wredA[j]);
            bB = fmaxf(bB, wredB[j]);
        }
        u64 pk = ((u64)__float_as_uint(bB) << 32) | (u64)__float_as_uint(bA);
        __hip_atomic_store(&slabAB[blk], pk, __ATOMIC_RELAXED, SCOPE);
    }

    // ---- md-independent pred math (overlaps peers' skew) ----
    // ce identity: log_sig(-x) = log_sig(x) - x  =>  ce = (1-t)*x - log_sig(x)
    float vals[12];
    #pragma unroll
    for (int q = 0; q < 12; ++q) vals[q] = 0.0f;
    float pv[4][4];
    #pragma unroll
    for (int s = 0; s < 4; ++s) {
        float tf = tfv[s];
        #pragma unroll
        for (int i = 0; i < 4; ++i) {
            float x = (s == 0) ? ((i==0)?x40.x:(i==1)?x41.x:(i==2)?x42.x:x43.x)
                    : (s == 1) ? ((i==0)?x40.y:(i==1)?x41.y:(i==2)?x42.y:x43.y)
                    : (s == 2) ? ((i==0)?x40.z:(i==1)?x41.z:(i==2)?x42.z:x43.z)
                               : ((i==0)?x40.w:(i==1)?x41.w:(i==2)?x42.w:x43.w);
            float e = __expf(-x);                       // e^{-x}
            float p = __builtin_amdgcn_rcpf(1.0f + e);  // sigmoid
            float emabs = (x >= 0.0f) ? e : __builtin_amdgcn_rcpf(e);  // e^{-|x|}
            float ls = fminf(x, 0.0f) - __logf(1.0f + emabs);          // log_sigmoid(x)
            float ce = (1.0f - tf) * x - ls;
            float p_t = p * tf + (1.0f - p) * (1.0f - tf);
            float om = 1.0f - p_t;
            float alpha_t = 0.25f * tf + 0.75f * (1.0f - tf);
            vals[i] += alpha_t * om * om * ce;
            pv[s][i] = p;
        }
    }

    // ---- wait for image md (poison-keyed: both sign bits must be clear) ----
    if (wv == 0) {
        float a = 0.0f, bb = 0.0f;
        if (lane < 16) {
            const int i = (b << 4) + lane;
            u64 v;
            for (;;) {
                v = __hip_atomic_load(&slabAB[i], __ATOMIC_RELAXED, SCOPE);
                if (!(v & 0x8000000080000000ull)) break;
                __builtin_amdgcn_s_sleep(1);
            }
            a  = __uint_as_float((u32)v);
            bb = __uint_as_float((u32)(v >> 32));
        }
        #pragma unroll
        for (int off = 32; off > 0; off >>= 1) {
            a  = fmaxf(a,  __shfl_xor(a,  off, 64));
            bb = fmaxf(bb, __shfl_xor(bb, off, 64));
        }
        if (lane == 0) { smdv[0] = a; smdv[1] = bb; }
    }
    __syncthreads();
    const float md = fmaxf(smdv[0], smdv[1]);
    const bool valid = (!emptyB) && (md > 0.0f);
    const float inv = 3.0f / fmaxf(md, 1e-12f);

    // ---- weights + IoU partials ----
    #pragma unroll
    for (int s = 0; s < 4; ++s) {
        float wgt = valid ? (1.0f + __expf(-absd[s] * inv)) : 1.0f;
        float tf = tfv[s];
        #pragma unroll
        for (int i = 0; i < 4; ++i) {
            vals[4 + i] += tf * pv[s][i] * wgt;
            vals[8 + i] += (pv[s][i] + tf) * wgt;
        }
    }

    // ---- block reduction; publish 12 nonneg partials (self-flagging) ----
    #pragma unroll
    for (int q = 0; q < 12; ++q) {
        float v = vals[q];
        #pragma unroll
        for (int o = 32; o > 0; o >>= 1) v += __shfl_down(v, o, 64);
        if (lane == 0) red[wv][q] = v;
    }
    __syncthreads();
    if (threadIdx.x < 12) {
        int q = threadIdx.x;
        float s = 0.0f;
        #pragma unroll
        for (int j = 0; j < 16; ++j) s += red[j][q];
        __hip_atomic_store((u32*)&partial[blk * 12 + q], __float_as_uint(s),
                           __ATOMIC_RELAXED, SCOPE);
    }

    // ---- block 0: flat final reduction over all 128 blocks ----
    if (blk == 0) {
        if (threadIdx.x < 96) {
            const int bi = threadIdx.x / 12;   // image
            const int qq = threadIdx.x % 12;
            float acc8[8];
            #pragma unroll
            for (int j = 0; j < 8; ++j) acc8[j] = 0.0f;
            for (int g2 = 0; g2 < 2; ++g2) {
                u32 raw[8];
                for (;;) {
                    bool bad = false;
                    #pragma unroll
                    for (int j = 0; j < 8; ++j)
                        raw[j] = __hip_atomic_load((u32*)&partial[((bi << 4) + g2 * 8 + j) * 12 + qq],
                                                   __ATOMIC_RELAXED, SCOPE);
                    #pragma unroll
                    for (int j = 0; j < 8; ++j) bad = bad || ((raw[j] >> 31) != 0u);
                    if (!bad) break;
                    __builtin_amdgcn_s_sleep(1);
                }
                #pragma unroll
                for (int j = 0; j < 8; ++j) acc8[j] += __uint_as_float(raw[j]);
            }
            fing[threadIdx.x] = ((acc8[0]+acc8[1])+(acc8[2]+acc8[3]))
                              + ((acc8[4]+acc8[5])+(acc8[6]+acc8[7]));
        }
        __syncthreads();
        if (threadIdx.x == 0) {
            const float coef[4] = {1.0f, 0.4f, 0.2f, 0.4f / 3.0f};
            float total = 0.0f;
            #pragma unroll
            for (int i = 0; i < 4; ++i) {
                float fm = 0.0f, ious = 0.0f;
                #pragma unroll
                for (int b2 = 0; b2 < BB; ++b2) {
                    fm += fing[b2 * 12 + i];
                    float in_ = fing[b2 * 12 + 4 + i];
                    float un  = fing[b2 * 12 + 8 + i] - in_;
                    ious += (in_ + 1e-6f) / (un + 1e-6f);
                }
                total += coef[i] * (fm / (float)NTOT + (1.0f - ious * 0.125f));
            }
            out[0] = total;
        }
    }
}

extern "C" void kernel_launch(void* const* d_in, const int* in_sizes, int n_in,
                              void* d_out, int out_size, void* d_ws, size_t ws_size,
                              hipStream_t stream) {
    const float* p0 = (const float*)d_in[0];
    const float* p1 = (const float*)d_in[1];
    const float* p2 = (const float*)d_in[2];
    const float* p3 = (const float*)d_in[3];
    const int* tgt = (const int*)d_in[4];
    float* out = (float*)d_out;

    char* w = (char*)d_ws;
    u64* slabAB    = (u64*)w;   w += 128 * sizeof(u64);
    float* partial = (float*)w; w += 128 * 12 * sizeof(float);

    k_fused<<<128, 1024, 0, stream>>>(p0, p1, p2, p3, tgt, slabAB, partial, out);
}

// Round 11
// 79.977 us; speedup vs baseline: 1.0713x; 1.0713x over previous
//
#include <hip/hip_runtime.h>
#include <math.h>

#define HH 256
#define WW 256
#define BB 8
#define NTOT (BB*HH*WW)
#define LARGE_F 1000000.0f
#define SCOPE __HIP_MEMORY_SCOPE_AGENT

typedef unsigned int u32;
typedef unsigned long long u64;

// ONE dispatch, 256 blocks x 512 threads (8 waves) -- measured optimum of the
// block-shape sweep (512x256: 44.5us, 256x512: ~38us, 128x1024: ~42us).
// 1 row/wave, 4 px/lane, 32 blocks/image. Cross-block sync is poison-keyed
// (published values are nonneg floats; 0xAA poison has sign bits set =>
// sign-clear == ready). CE uses log_sig(-x) = log_sig(x) - x identity.

__device__ __forceinline__ float wave_max(float v) {
    #pragma unroll
    for (int off = 32; off > 0; off >>= 1)
        v = fmaxf(v, __shfl_xor(v, off, 64));
    return v;
}

// ballot-build row's 256-bit mask into LDS (wave-uniform call; 64 lanes active)
__device__ __forceinline__ void build_row(const int* __restrict__ tgt, int tb,
                                          int row, int lane, u64 (*sm)[4]) {
    const int base = tb + (row << 8) + lane;
    u64 w0 = __ballot(tgt[base]       == 0);
    u64 w1 = __ballot(tgt[base + 64]  == 0);
    u64 w2 = __ballot(tgt[base + 128] == 0);
    u64 w3 = __ballot(tgt[base + 192] == 0);
    if (lane == 0) { sm[row][0] = w0; sm[row][1] = w1; sm[row][2] = w2; sm[row][3] = w3; }
}

// nearest set-bit distances within one 256-bit row mask (bit set = feature)
__device__ __forceinline__ void row_check(const u64* __restrict__ row,
                                          int k0, int r0, int c0, float dh2f,
                                          float* bestA, float* bestB) {
    u64 m0 = row[0], m1 = row[1], m2 = row[2], m3 = row[3];
    u64 n0 = ~m0, n1 = ~m1, n2 = ~m2, n3 = ~m3;

    int HbA = -1;
    if (k0 > 0 && m0) HbA = 63  - __builtin_clzll(m0);
    if (k0 > 1 && m1) HbA = 127 - __builtin_clzll(m1);
    if (k0 > 2 && m2) HbA = 191 - __builtin_clzll(m2);
    int RaA = 1 << 20;
    if (k0 < 3 && m3) RaA = 192 + __builtin_ctzll(m3);
    if (k0 < 2 && m2) RaA = 128 + __builtin_ctzll(m2);
    if (k0 < 1 && m1) RaA = 64  + __builtin_ctzll(m1);

    int HbB = -1;
    if (k0 > 0 && n0) HbB = 63  - __builtin_clzll(n0);
    if (k0 > 1 && n1) HbB = 127 - __builtin_clzll(n1);
    if (k0 > 2 && n2) HbB = 191 - __builtin_clzll(n2);
    int RaB = 1 << 20;
    if (k0 < 3 && n3) RaB = 192 + __builtin_ctzll(n3);
    if (k0 < 2 && n2) RaB = 128 + __builtin_ctzll(n2);
    if (k0 < 1 && n1) RaB = 64  + __builtin_ctzll(n1);

    u64 mk = (k0 == 0) ? m0 : (k0 == 1) ? m1 : (k0 == 2) ? m2 : m3;
    u64 nk = ~mk;
    const int base = 64 * k0;

    #pragma unroll
    for (int s = 0; s < 4; ++s) {
        int r = r0 + s, w = c0 + s;
        u64 le = (2ull << r) - 1ull;
        u64 ge = (~0ull) << r;
        {
            u64 lo = mk & le, hi = mk & ge;
            int L = lo ? (base + 63 - __builtin_clzll(lo)) : HbA;
            int R = hi ? (base + __builtin_ctzll(hi)) : RaA;
            int dl = (L >= 0) ? (w - L) : (1 << 20);
            int dr = R - w;
            float f = (float)min(dl, dr);
            bestA[s] = fminf(bestA[s], __builtin_fmaf(f, f, dh2f));
        }
        {
            u64 lo = nk & le, hi = nk & ge;
            int L = lo ? (base + 63 - __builtin_clzll(lo)) : HbB;
            int R = hi ? (base + __builtin_ctzll(hi)) : RaB;
            int dl = (L >= 0) ? (w - L) : (1 << 20);
            int dr = R - w;
            float f = (float)min(dl, dr);
            bestB[s] = fminf(bestB[s], __builtin_fmaf(f, f, dh2f));
        }
    }
}

__global__ void __launch_bounds__(512) k_fused(
    const float* __restrict__ p0, const float* __restrict__ p1,
    const float* __restrict__ p2, const float* __restrict__ p3,
    const int* __restrict__ tgt,
    u64* __restrict__ slabAB, float* __restrict__ partial,
    float* __restrict__ out)
{
    const int blk  = blockIdx.x;
    const int b    = blk >> 5;        // image (32 blocks per image)
    const int slab = blk & 31;        // 8-row slab
    const int wv   = threadIdx.x >> 6;   // 0..7
    const int lane = threadIdx.x & 63;
    const int h    = slab * 8 + wv;   // this wave's row
    const int c0   = lane * 4;
    const int k0   = c0 >> 6;
    const int r0   = c0 & 63;
    const int tb   = b << 16;
    const int rowbase = tb + (h << 8);

    __shared__ u64 sm[HH][4];
    __shared__ float wredA[8], wredB[8], smdv[2];
    __shared__ float red[8][12];
    __shared__ float fing[96];

    // ---- cooperative initial window FIRST (critical path into EDT):
    //      rows [slab*8-8, slab*8+15], 3 rows per wave ----
    const int lo0 = slab * 8 - 8;
    #pragma unroll
    for (int j = 0; j < 3; ++j) {
        int row = lo0 + wv * 3 + j;
        if (row >= 0 && row < HH) build_row(tgt, tb, row, lane, sm);
    }

    // ---- pred loads issued now; consumed only after EDT ----
    const int idx = rowbase + c0;
    float4 x40 = *(const float4*)(p0 + idx);
    float4 x41 = *(const float4*)(p1 + idx);
    float4 x42 = *(const float4*)(p2 + idx);
    float4 x43 = *(const float4*)(p3 + idx);

    __syncthreads();
    int winLo = max(lo0, 0);
    int winHi = min(lo0 + 23, HH - 1);

    // ---- EDT ring search (wave-uniform loop, lazy row extension) ----
    float bestA[4] = {1e30f, 1e30f, 1e30f, 1e30f};
    float bestB[4] = {1e30f, 1e30f, 1e30f, 1e30f};

    row_check(&sm[h][0], k0, r0, c0, 0.0f, bestA, bestB);
    float bmax = 0.0f;
    #pragma unroll
    for (int s = 0; s < 4; ++s) bmax = fmaxf(bmax, fmaxf(bestA[s], bestB[s]));
    float wbmax = wave_max(bmax);

    for (int dh = 1; dh < HH; ++dh) {
        float dh2f = (float)(dh * dh);
        if (dh2f >= wbmax) break;                 // uniform on all lanes
        int hd = h - dh, hu = h + dh;
        if (hd >= 0) {
            if (hd < winLo) { build_row(tgt, tb, hd, lane, sm); winLo = hd; }
            row_check(&sm[hd][0], k0, r0, c0, dh2f, bestA, bestB);
        }
        if (hu < HH) {
            if (hu > winHi) { build_row(tgt, tb, hu, lane, sm); winHi = hu; }
            row_check(&sm[hu][0], k0, r0, c0, dh2f, bestA, bestB);
        }
        bmax = 0.0f;
        #pragma unroll
        for (int s = 0; s < 4; ++s) bmax = fmaxf(bmax, fmaxf(bestA[s], bestB[s]));
        wbmax = wave_max(bmax);
    }

    // best >= 1e29 only if that mask is empty image-wide => dist = exactly 1e6.
    const bool emptyB = (bestB[0] >= 1e29f);      // no t==1 pixels
    const u64 mkown = sm[h][k0];
    float absd[4], tfv[4];
    float wmA = -1.0f, wmB = -1.0f;
    #pragma unroll
    for (int s = 0; s < 4; ++s) {
        float dA = (bestA[s] >= 1e29f) ? LARGE_F : sqrtf(bestA[s]);
        float dB = (bestB[s] >= 1e29f) ? LARGE_F : sqrtf(bestB[s]);
        wmA = fmaxf(wmA, dA);
        wmB = fmaxf(wmB, dB);
        int bit = (int)((mkown >> (r0 + s)) & 1ull);   // set => t==0
        tfv[s]  = bit ? 0.0f : 1.0f;
        absd[s] = bit ? dB : dA;
    }
    #pragma unroll
    for (int off = 32; off > 0; off >>= 1) {
        wmA = fmaxf(wmA, __shfl_down(wmA, off, 64));
        wmB = fmaxf(wmB, __shfl_down(wmB, off, 64));
    }
    if (lane == 0) { wredA[wv] = wmA; wredB[wv] = wmB; }
    __syncthreads();
    if (threadIdx.x == 0) {
        float bA = wredA[0], bB = wredB[0];
        #pragma unroll
        for (int j = 1; j < 8; ++j) {
            bA = fmaxf(bA, wredA[j]);
            bB = fmaxf(bB, wredB[j]);
        }
        u64 pk = ((u64)__float_as_uint(bB) << 32) | (u64)__float_as_uint(bA);
        __hip_atomic_store(&slabAB[blk], pk, __ATOMIC_RELAXED, SCOPE);
    }

    // ---- md-independent pred math (overlaps peers' skew) ----
    // ce identity: log_sig(-x) = log_sig(x) - x  =>  ce = (1-t)*x - log_sig(x)
    float vals[12];
    #pragma unroll
    for (int q = 0; q < 12; ++q) vals[q] = 0.0f;
    float pv[4][4];
    #pragma unroll
    for (int s = 0; s < 4; ++s) {
        float tf = tfv[s];
        #pragma unroll
        for (int i = 0; i < 4; ++i) {
            float x = (s == 0) ? ((i==0)?x40.x:(i==1)?x41.x:(i==2)?x42.x:x43.x)
                    : (s == 1) ? ((i==0)?x40.y:(i==1)?x41.y:(i==2)?x42.y:x43.y)
                    : (s == 2) ? ((i==0)?x40.z:(i==1)?x41.z:(i==2)?x42.z:x43.z)
                               : ((i==0)?x40.w:(i==1)?x41.w:(i==2)?x42.w:x43.w);
            float e = __expf(-x);                       // e^{-x}
            float p = __builtin_amdgcn_rcpf(1.0f + e);  // sigmoid
            float emabs = (x >= 0.0f) ? e : __builtin_amdgcn_rcpf(e);  // e^{-|x|}
            float ls = fminf(x, 0.0f) - __logf(1.0f + emabs);          // log_sigmoid(x)
            float ce = (1.0f - tf) * x - ls;
            float p_t = p * tf + (1.0f - p) * (1.0f - tf);
            float om = 1.0f - p_t;
            float alpha_t = 0.25f * tf + 0.75f * (1.0f - tf);
            vals[i] += alpha_t * om * om * ce;
            pv[s][i] = p;
        }
    }

    // ---- wait for image md (poison-keyed: both sign bits must be clear) ----
    if (wv == 0) {
        float a = 0.0f, bb = 0.0f;
        if (lane < 32) {
            const int i = (b << 5) + lane;
            u64 v;
            for (;;) {
                v = __hip_atomic_load(&slabAB[i], __ATOMIC_RELAXED, SCOPE);
                if (!(v & 0x8000000080000000ull)) break;
                __builtin_amdgcn_s_sleep(1);
            }
            a  = __uint_as_float((u32)v);
            bb = __uint_as_float((u32)(v >> 32));
        }
        #pragma unroll
        for (int off = 32; off > 0; off >>= 1) {
            a  = fmaxf(a,  __shfl_xor(a,  off, 64));
            bb = fmaxf(bb, __shfl_xor(bb, off, 64));
        }
        if (lane == 0) { smdv[0] = a; smdv[1] = bb; }
    }
    __syncthreads();
    const float md = fmaxf(smdv[0], smdv[1]);
    const bool valid = (!emptyB) && (md > 0.0f);
    const float inv = 3.0f / fmaxf(md, 1e-12f);

    // ---- weights + IoU partials ----
    #pragma unroll
    for (int s = 0; s < 4; ++s) {
        float wgt = valid ? (1.0f + __expf(-absd[s] * inv)) : 1.0f;
        float tf = tfv[s];
        #pragma unroll
        for (int i = 0; i < 4; ++i) {
            vals[4 + i] += tf * pv[s][i] * wgt;
            vals[8 + i] += (pv[s][i] + tf) * wgt;
        }
    }

    // ---- block reduction; publish 12 nonneg partials (self-flagging) ----
    #pragma unroll
    for (int q = 0; q < 12; ++q) {
        float v = vals[q];
        #pragma unroll
        for (int o = 32; o > 0; o >>= 1) v += __shfl_down(v, o, 64);
        if (lane == 0) red[wv][q] = v;
    }
    __syncthreads();
    if (threadIdx.x < 12) {
        int q = threadIdx.x;
        float s = 0.0f;
        #pragma unroll
        for (int j = 0; j < 8; ++j) s += red[j][q];
        __hip_atomic_store((u32*)&partial[blk * 12 + q], __float_as_uint(s),
                           __ATOMIC_RELAXED, SCOPE);
    }

    // ---- block 0: flat final reduction over all 256 blocks ----
    if (blk == 0) {
        if (threadIdx.x < 96) {
            const int bi = threadIdx.x / 12;   // image
            const int qq = threadIdx.x % 12;
            float acc8[8];
            #pragma unroll
            for (int j = 0; j < 8; ++j) acc8[j] = 0.0f;
            for (int g4 = 0; g4 < 4; ++g4) {
                u32 raw[8];
                for (;;) {
                    bool bad = false;
                    #pragma unroll
                    for (int j = 0; j < 8; ++j)
                        raw[j] = __hip_atomic_load((u32*)&partial[((bi << 5) + g4 * 8 + j) * 12 + qq],
                                                   __ATOMIC_RELAXED, SCOPE);
                    #pragma unroll
                    for (int j = 0; j < 8; ++j) bad = bad || ((raw[j] >> 31) != 0u);
                    if (!bad) break;
                    __builtin_amdgcn_s_sleep(1);
                }
                #pragma unroll
                for (int j = 0; j < 8; ++j) acc8[j] += __uint_as_float(raw[j]);
            }
            fing[threadIdx.x] = ((acc8[0]+acc8[1])+(acc8[2]+acc8[3]))
                              + ((acc8[4]+acc8[5])+(acc8[6]+acc8[7]));
        }
        __syncthreads();
        if (threadIdx.x == 0) {
            const float coef[4] = {1.0f, 0.4f, 0.2f, 0.4f / 3.0f};
            float total = 0.0f;
            #pragma unroll
            for (int i = 0; i < 4; ++i) {
                float fm = 0.0f, ious = 0.0f;
                #pragma unroll
                for (int b2 = 0; b2 < BB; ++b2) {
                    fm += fing[b2 * 12 + i];
                    float in_ = fing[b2 * 12 + 4 + i];
                    float un  = fing[b2 * 12 + 8 + i] - in_;
                    ious += (in_ + 1e-6f) / (un + 1e-6f);
                }
                total += coef[i] * (fm / (float)NTOT + (1.0f - ious * 0.125f));
            }
            out[0] = total;
        }
    }
}

extern "C" void kernel_launch(void* const* d_in, const int* in_sizes, int n_in,
                              void* d_out, int out_size, void* d_ws, size_t ws_size,
                              hipStream_t stream) {
    const float* p0 = (const float*)d_in[0];
    const float* p1 = (const float*)d_in[1];
    const float* p2 = (const float*)d_in[2];
    const float* p3 = (const float*)d_in[3];
    const int* tgt = (const int*)d_in[4];
    float* out = (float*)d_out;

    char* w = (char*)d_ws;
    u64* slabAB    = (u64*)w;   w += 256 * sizeof(u64);
    float* partial = (float*)w; w += 256 * 12 * sizeof(float);

    k_fused<<<BB * 32, 512, 0, stream>>>(p0, p1, p2, p3, tgt, slabAB, partial, out);
}